// Round 1
// baseline (1069.484 us; speedup 1.0000x reference)
//
#include <hip/hip_runtime.h>
#include <stdint.h>

#define B_    16
#define CIN   256
#define COUT  128
#define VLOW  10242
#define NUP   40962
#define KTAP  7
#define FTOT  (KTAP * COUT)   // 896
#define VK    (VLOW * KTAP)   // 71694
#define NBLK  41              // ceil(NUP/1024) scan blocks

typedef __attribute__((ext_vector_type(4))) float  floatx4;
typedef __attribute__((ext_vector_type(8))) short  bf16x8;

__device__ __forceinline__ unsigned short f2bf(float f) {
    union { float f; unsigned int u; } x; x.f = f;
    unsigned int r = x.u + 0x7FFFu + ((x.u >> 16) & 1u);  // RNE
    return (unsigned short)(r >> 16);
}
__device__ __forceinline__ float bflo(unsigned int u) {
    union { unsigned int u; float f; } x; x.u = u << 16; return x.f;
}
__device__ __forceinline__ float bfhi(unsigned int u) {
    union { unsigned int u; float f; } x; x.u = u & 0xFFFF0000u; return x.f;
}

// ---------- CSR construction (deterministic int work, once per launch) ----------

__global__ void count_kernel(const int* __restrict__ neigh, int* __restrict__ counts) {
    int i = blockIdx.x * blockDim.x + threadIdx.x;
    if (i < VK) atomicAdd(&counts[neigh[i]], 1);
}

__global__ __launch_bounds__(1024)
void scan_local(const int* __restrict__ counts, int* __restrict__ offs, int* __restrict__ bsum) {
    __shared__ int s[1024];
    const int t = threadIdx.x;
    const int idx = blockIdx.x * 1024 + t;
    int v = (idx < NUP) ? counts[idx] : 0;
    s[t] = v;
    __syncthreads();
    int acc = v;
    for (int off = 1; off < 1024; off <<= 1) {
        int add = (t >= off) ? s[t - off] : 0;
        __syncthreads();
        acc += add;
        s[t] = acc;
        __syncthreads();
    }
    if (idx < NUP) offs[idx] = acc - v;      // block-local exclusive
    if (t == 1023) bsum[blockIdx.x] = acc;   // block total
}

__global__ void scan_sums(const int* __restrict__ bsum, int* __restrict__ bbase) {
    if (threadIdx.x == 0) {
        int r = 0;
        for (int j = 0; j < NBLK; ++j) { bbase[j] = r; r += bsum[j]; }
    }
}

__global__ void fill_csr(const int* __restrict__ neigh, const int* __restrict__ offs,
                         const int* __restrict__ bbase, int* __restrict__ cursor,
                         int* __restrict__ csr) {
    int i = blockIdx.x * blockDim.x + threadIdx.x;
    if (i < VK) {
        int n = neigh[i];
        int p = atomicAdd(&cursor[n], 1);
        csr[offs[n] + bbase[n >> 10] + p] = i;
    }
}

// ---------- Phase 1: GEMM -> y (bf16) ----------
// Block: 256 threads (4 waves). Tile: 128 v x 128 f (f-tile == one tap k).
// LDS: A [128][40] bf16, B [128][40] bf16 (shared pool, reused for epilogue transpose).
__global__ __launch_bounds__(256)
void gemm_y(const float* __restrict__ x,     // [G, CIN, VLOW] (group base pre-offset)
            const float* __restrict__ w,     // [CIN, FTOT]
            const float* __restrict__ bias,  // [FTOT]
            unsigned short* __restrict__ y)  // [G, VLOW, FTOT] bf16
{
    __shared__ unsigned short smem[10240];
    unsigned short* lds_a = smem;            // [128][40]
    unsigned short* lds_b = smem + 5120;     // [128][40]

    const int t    = threadIdx.x;
    const int vt   = blockIdx.x;       // 0..80
    const int ktap = blockIdx.y;       // 0..6
    const int bl   = blockIdx.z;       // batch within group
    const int v0   = vt * 128;
    const int f0   = ktap * 128;

    const int lane = t & 63;
    const int wid  = t >> 6;
    const int wv   = wid & 1;
    const int wf   = wid >> 1;
    const int mrow = lane & 15;
    const int quad = lane >> 4;
    const int kb   = quad * 8;

    floatx4 acc[4][4];
#pragma unroll
    for (int i = 0; i < 4; i++)
#pragma unroll
        for (int j = 0; j < 4; j++) acc[i][j] = (floatx4)0.0f;

    const int sv = t & 127;
    const int sc = (t >> 7) * 16;

    const float* xb = x + (size_t)bl * CIN * VLOW;
    int vg = v0 + sv; if (vg > VLOW - 1) vg = VLOW - 1;

    for (int kc = 0; kc < CIN; kc += 32) {
        float av[16], bv16[16];
#pragma unroll
        for (int cc = 0; cc < 16; cc++) {
            av[cc]   = xb[(size_t)(kc + sc + cc) * VLOW + vg];
            bv16[cc] = w[(size_t)(kc + sc + cc) * FTOT + f0 + sv];
        }
        __syncthreads();   // previous tile fully consumed
        unsigned int pa[8], pb[8];
#pragma unroll
        for (int q = 0; q < 8; q++) {
            pa[q] = (unsigned int)f2bf(av[2*q])   | ((unsigned int)f2bf(av[2*q+1])   << 16);
            pb[q] = (unsigned int)f2bf(bv16[2*q]) | ((unsigned int)f2bf(bv16[2*q+1]) << 16);
        }
        *(uint4*)&lds_a[sv * 40 + sc]     = make_uint4(pa[0], pa[1], pa[2], pa[3]);
        *(uint4*)&lds_a[sv * 40 + sc + 8] = make_uint4(pa[4], pa[5], pa[6], pa[7]);
        *(uint4*)&lds_b[sv * 40 + sc]     = make_uint4(pb[0], pb[1], pb[2], pb[3]);
        *(uint4*)&lds_b[sv * 40 + sc + 8] = make_uint4(pb[4], pb[5], pb[6], pb[7]);
        __syncthreads();

        bf16x8 fa[4], fb[4];
#pragma unroll
        for (int i = 0; i < 4; i++)
            fa[i] = *(const bf16x8*)&lds_a[(wv * 64 + i * 16 + mrow) * 40 + kb];
#pragma unroll
        for (int j = 0; j < 4; j++)
            fb[j] = *(const bf16x8*)&lds_b[(wf * 64 + j * 16 + mrow) * 40 + kb];
#pragma unroll
        for (int i = 0; i < 4; i++)
#pragma unroll
            for (int j = 0; j < 4; j++)
                acc[i][j] = __builtin_amdgcn_mfma_f32_16x16x32_bf16(fa[i], fb[j], acc[i][j], 0, 0, 0);
    }

    // epilogue: +bias, bf16, LDS transpose (stride 130 shorts -> 2-way banks), coalesced 16B stores
    float bvv[4];
#pragma unroll
    for (int j = 0; j < 4; j++) bvv[j] = bias[f0 + wf * 64 + j * 16 + mrow];

    unsigned short* yb = y + (size_t)bl * VLOW * FTOT;
#pragma unroll
    for (int half = 0; half < 2; ++half) {
        __syncthreads();
        if (wv == half) {
#pragma unroll
            for (int i = 0; i < 4; i++)
#pragma unroll
                for (int j = 0; j < 4; j++)
#pragma unroll
                    for (int r = 0; r < 4; r++) {
                        int vl = i * 16 + quad * 4 + r;            // 0..63
                        int c  = wf * 64 + j * 16 + mrow;          // 0..127
                        smem[vl * 130 + c] = f2bf(acc[i][j][r] + bvv[j]);
                    }
        }
        __syncthreads();
        int row = t >> 2, cb = (t & 3) * 32;
        int v = v0 + half * 64 + row;
        if (v < VLOW) {
            unsigned int tmp[16];
#pragma unroll
            for (int q = 0; q < 16; q++)
                tmp[q] = *(const unsigned int*)&smem[row * 130 + cb + q * 2];
            uint4* dst = (uint4*)(yb + (size_t)v * FTOT + f0 + cb);
            dst[0] = make_uint4(tmp[0],  tmp[1],  tmp[2],  tmp[3]);
            dst[1] = make_uint4(tmp[4],  tmp[5],  tmp[6],  tmp[7]);
            dst[2] = make_uint4(tmp[8],  tmp[9],  tmp[10], tmp[11]);
            dst[3] = make_uint4(tmp[12], tmp[13], tmp[14], tmp[15]);
        }
    }
}

// ---------- Phase 2: CSR gather -> out (each element written exactly once) ----------
// Block: 256 threads, owns 64 up-vertices x one batch. Wave w: 16 vertices, lanes own c-pairs.
__global__ __launch_bounds__(256)
void gather_out(const unsigned short* __restrict__ y, const int* __restrict__ offs,
                const int* __restrict__ bbase, const int* __restrict__ counts,
                const int* __restrict__ csr, float* __restrict__ out, int b_base)
{
    __shared__ float lt[64 * 130];
    const int t = threadIdx.x, lane = t & 63, wvv = t >> 6;
    const int n0 = blockIdx.x * 64;
    const int bl = blockIdx.y;
    const unsigned short* yb = y + (size_t)bl * VLOW * FTOT;

    for (int nl = 0; nl < 16; ++nl) {
        int nloc = wvv * 16 + nl;
        int n = n0 + nloc;
        float a0 = 0.0f, a1 = 0.0f;
        if (n < NUP) {
            int st  = offs[n] + bbase[n >> 10];
            int cnt = counts[n];
            for (int e = 0; e < cnt; ++e) {
                int i = csr[st + e];
                int v = i / 7, k = i - v * 7;
                unsigned int u = *(const unsigned int*)(yb + (size_t)v * FTOT + k * COUT + lane * 2);
                a0 += bflo(u);
                a1 += bfhi(u);
            }
            float inv = cnt ? 1.0f / (float)cnt : 0.0f;
            a0 *= inv; a1 *= inv;
        }
        lt[nloc * 130 + lane * 2]     = a0;
        lt[nloc * 130 + lane * 2 + 1] = a1;
    }
    __syncthreads();

    float* ob = out + (size_t)(b_base + bl) * COUT * NUP;
    int nl2 = t & 63, n = n0 + nl2;
    if (n < NUP) {
#pragma unroll
        for (int rr = 0; rr < 32; ++rr) {
            int c = rr * 4 + (t >> 6);
            ob[(size_t)c * NUP + n] = lt[nl2 * 130 + c];
        }
    }
}

// ---------- launch ----------

extern "C" void kernel_launch(void* const* d_in, const int* in_sizes, int n_in,
                              void* d_out, int out_size, void* d_ws, size_t ws_size,
                              hipStream_t stream) {
    const float* x     = (const float*)d_in[0];
    const float* w     = (const float*)d_in[1];
    const float* bias  = (const float*)d_in[2];
    const int*   neigh = (const int*)d_in[3];
    float* out = (float*)d_out;

    char* p = (char*)d_ws;
    const size_t a_nup = ((size_t)NUP * 4 + 255) & ~(size_t)255;   // 164096
    int* counts = (int*)p;           p += a_nup;
    int* cursor = (int*)p;           p += a_nup;                   // contiguous with counts
    int* offs   = (int*)p;           p += a_nup;
    int* bsum   = (int*)p;           p += 256;
    int* bbase  = (int*)p;           p += 256;
    int* csr    = (int*)p;           p += ((size_t)VK * 4 + 255) & ~(size_t)255;
    unsigned short* y = (unsigned short*)p;

    size_t meta     = (size_t)((char*)y - (char*)d_ws);
    size_t y_per_b  = (size_t)VLOW * FTOT * 2;                     // 18.35 MB bf16
    int G = 4;                                                     // batches per y-group
    while (G > 1 && meta + (size_t)G * y_per_b > ws_size) G >>= 1;

    hipMemsetAsync(counts, 0, a_nup * 2, stream);                  // counts + cursor

    count_kernel<<<(VK + 255) / 256, 256, 0, stream>>>(neigh, counts);
    scan_local<<<NBLK, 1024, 0, stream>>>(counts, offs, bsum);
    scan_sums<<<1, 64, 0, stream>>>(bsum, bbase);
    fill_csr<<<(VK + 255) / 256, 256, 0, stream>>>(neigh, offs, bbase, cursor, csr);

    for (int bg = 0; bg < B_; bg += G) {
        gemm_y<<<dim3(81, KTAP, G), 256, 0, stream>>>(x + (size_t)bg * CIN * VLOW, w, bias, y);
        gather_out<<<dim3(641, G), 256, 0, stream>>>(y, offs, bbase, counts, csr, out, bg);
    }
}

// Round 3
// 1011.723 us; speedup vs baseline: 1.0571x; 1.0571x over previous
//
#include <hip/hip_runtime.h>
#include <stdint.h>

#define B_    16
#define CIN   256
#define COUT  128
#define VLOW  10242
#define NUP   40962
#define KTAP  7
#define FTOT  (KTAP * COUT)   // 896
#define VK    (VLOW * KTAP)   // 71694
#define NBLK  41              // ceil(NUP/1024) scan blocks
#define VPAD  10368           // 81*128, padded v rows for xT

typedef __attribute__((ext_vector_type(4))) float  floatx4;
typedef __attribute__((ext_vector_type(8))) short  bf16x8;

typedef __attribute__((address_space(3))) unsigned char       lds_u8;
typedef const __attribute__((address_space(1))) unsigned char gbl_u8;

__device__ __forceinline__ void gl_lds16(const unsigned short* g, unsigned short* l) {
    // 64 lanes x 16 B -> LDS[base + lane*16]; global src is per-lane
    __builtin_amdgcn_global_load_lds((gbl_u8*)g, (lds_u8*)l, 16, 0, 0);
}

__device__ __forceinline__ unsigned short f2bf(float f) {
    union { float f; unsigned int u; } x; x.f = f;
    unsigned int r = x.u + 0x7FFFu + ((x.u >> 16) & 1u);  // RNE
    return (unsigned short)(r >> 16);
}
__device__ __forceinline__ float bflo(unsigned int u) {
    union { unsigned int u; float f; } x; x.u = u << 16; return x.f;
}
__device__ __forceinline__ float bfhi(unsigned int u) {
    union { unsigned int u; float f; } x; x.u = u & 0xFFFF0000u; return x.f;
}

// ---------- CSR construction ----------

__global__ void count_kernel(const int* __restrict__ neigh, int* __restrict__ counts) {
    int i = blockIdx.x * blockDim.x + threadIdx.x;
    if (i < VK) atomicAdd(&counts[neigh[i]], 1);
}

__global__ __launch_bounds__(1024)
void scan_local(const int* __restrict__ counts, int* __restrict__ offs, int* __restrict__ bsum) {
    __shared__ int s[1024];
    const int t = threadIdx.x;
    const int idx = blockIdx.x * 1024 + t;
    int v = (idx < NUP) ? counts[idx] : 0;
    s[t] = v;
    __syncthreads();
    int acc = v;
    for (int off = 1; off < 1024; off <<= 1) {
        int add = (t >= off) ? s[t - off] : 0;
        __syncthreads();
        acc += add;
        s[t] = acc;
        __syncthreads();
    }
    if (idx < NUP) offs[idx] = acc - v;
    if (t == 1023) bsum[blockIdx.x] = acc;
}

__global__ void scan_sums(const int* __restrict__ bsum, int* __restrict__ bbase) {
    if (threadIdx.x == 0) {
        int r = 0;
        for (int j = 0; j < NBLK; ++j) { bbase[j] = r; r += bsum[j]; }
    }
}

__global__ void fill_csr(const int* __restrict__ neigh, const int* __restrict__ offs,
                         const int* __restrict__ bbase, int* __restrict__ cursor,
                         int* __restrict__ csr) {
    int i = blockIdx.x * blockDim.x + threadIdx.x;
    if (i < VK) {
        int n = neigh[i];
        int p = atomicAdd(&cursor[n], 1);
        csr[offs[n] + bbase[n >> 10] + p] = i;
    }
}

// ---------- fp32 [256][C] -> bf16 [CPAD][256] transpose+convert ----------
// src batch stride 256*C, dst batch stride CPAD*256. Zero-fills rows >= CLIM.
__global__ __launch_bounds__(256)
void transpose256(const float* __restrict__ src, unsigned short* __restrict__ dst,
                  int C, int CLIM, int CPAD)
{
    __shared__ unsigned short lt[64][72];
    const int t  = threadIdx.x;
    const int v0 = blockIdx.x * 64;
    const int c0 = blockIdx.y * 64;
    const int z  = blockIdx.z;
    const float* s = src + (size_t)z * 256 * C;
    unsigned short* d = dst + (size_t)z * CPAD * 256;

#pragma unroll
    for (int p = 0; p < 16; ++p) {
        int cr = c0 + p * 4 + (t >> 6);
        int v  = v0 + (t & 63);
        float val = (v < CLIM) ? s[(size_t)cr * C + v] : 0.0f;
        lt[t & 63][p * 4 + (t >> 6)] = f2bf(val);
    }
    __syncthreads();
    // 256 threads x 16 B = 2048 shorts/iter; 64x64 tile = 4096 shorts -> exactly 2 iters
#pragma unroll
    for (int p = 0; p < 2; ++p) {
        int vl = p * 32 + (t >> 3);
        int v  = v0 + vl;
        if (v < CPAD) {
            uint4 val = *(const uint4*)&lt[vl][(t & 7) * 8];
            *(uint4*)&d[(size_t)v * 256 + c0 + (t & 7) * 8] = val;
        }
    }
}

// ---------- Phase 1: GEMM -> y (bf16), global_load_lds staging ----------
// Block: 256 threads (4 waves). Tile: 128 v x 128 f (f-tile == one tap k).
// LDS: A [128][32] bf16 linear, B [128][32] bf16 linear (pool reused for epilogue).
__global__ __launch_bounds__(256)
void gemm_y(const unsigned short* __restrict__ xT,  // [G][VPAD][256] bf16
            const unsigned short* __restrict__ wT,  // [896][256] bf16
            const float* __restrict__ bias,         // [FTOT]
            unsigned short* __restrict__ y)         // [G][VLOW][FTOT] bf16
{
    __shared__ unsigned short smem[8320];
    unsigned short* lds_a = smem;           // [128][32]
    unsigned short* lds_b = smem + 4096;    // [128][32]

    const int t    = threadIdx.x;
    const int vt   = blockIdx.x;       // 0..80
    const int ktap = blockIdx.y;       // 0..6
    const int bl   = blockIdx.z;       // batch within group
    const int v0   = vt * 128;
    const int f0   = ktap * 128;

    const int lane = t & 63;
    const int wid  = t >> 6;
    const int wv   = wid & 1;
    const int wf   = wid >> 1;
    const int mrow = lane & 15;
    const int quad = lane >> 4;
    const int kb   = quad * 8;

    floatx4 acc[4][4];
#pragma unroll
    for (int i = 0; i < 4; i++)
#pragma unroll
        for (int j = 0; j < 4; j++) acc[i][j] = (floatx4)0.0f;

    // staging: wave w stages A rows [32w, 32w+32) and same B rows.
    // one instr covers 16 rows: lane l -> row l>>2, 16B chunk l&3 (row = 64 B = 32 bf16)
    const int srow = (lane >> 2);
    const int scol = (lane & 3) << 3;   // bf16 elems
    const unsigned short* gA0 = xT + (((size_t)bl * VPAD + v0 + (2 * wid) * 16 + srow) << 8) + scol;
    const unsigned short* gA1 = gA0 + (16 << 8);
    const unsigned short* gB0 = wT + (((size_t)f0 + (2 * wid) * 16 + srow) << 8) + scol;
    const unsigned short* gB1 = gB0 + (16 << 8);
    unsigned short* lA0 = lds_a + (2 * wid) * 512;
    unsigned short* lA1 = lA0 + 512;
    unsigned short* lB0 = lds_b + (2 * wid) * 512;
    unsigned short* lB1 = lB0 + 512;

    for (int kc = 0; kc < CIN; kc += 32) {
        __syncthreads();                 // previous tile fully consumed
        gl_lds16(gA0 + kc, lA0);
        gl_lds16(gA1 + kc, lA1);
        gl_lds16(gB0 + kc, lB0);
        gl_lds16(gB1 + kc, lB1);
        __syncthreads();                 // loads drained (vmcnt(0) before barrier)

        bf16x8 fa[4], fb[4];
#pragma unroll
        for (int i = 0; i < 4; i++)
            fa[i] = *(const bf16x8*)&lds_a[(wv * 64 + i * 16 + mrow) * 32 + kb];
#pragma unroll
        for (int j = 0; j < 4; j++)
            fb[j] = *(const bf16x8*)&lds_b[(wf * 64 + j * 16 + mrow) * 32 + kb];
#pragma unroll
        for (int i = 0; i < 4; i++)
#pragma unroll
            for (int j = 0; j < 4; j++)
                acc[i][j] = __builtin_amdgcn_mfma_f32_16x16x32_bf16(fa[i], fb[j], acc[i][j], 0, 0, 0);
    }

    // epilogue: +bias, bf16, LDS transpose, coalesced 16B stores
    float bvv[4];
#pragma unroll
    for (int j = 0; j < 4; j++) bvv[j] = bias[f0 + wf * 64 + j * 16 + mrow];

    unsigned short* yb = y + (size_t)bl * VLOW * FTOT;
#pragma unroll
    for (int half = 0; half < 2; ++half) {
        __syncthreads();
        if (wv == half) {
#pragma unroll
            for (int i = 0; i < 4; i++)
#pragma unroll
                for (int j = 0; j < 4; j++)
#pragma unroll
                    for (int r = 0; r < 4; r++) {
                        int vl = i * 16 + quad * 4 + r;            // 0..63
                        int c  = wf * 64 + j * 16 + mrow;          // 0..127
                        smem[vl * 130 + c] = f2bf(acc[i][j][r] + bvv[j]);
                    }
        }
        __syncthreads();
        int row = t >> 2, cb = (t & 3) * 32;
        int v = v0 + half * 64 + row;
        if (v < VLOW) {
            unsigned int tmp[16];
#pragma unroll
            for (int q = 0; q < 16; q++)
                tmp[q] = *(const unsigned int*)&smem[row * 130 + cb + q * 2];
            uint4* dst = (uint4*)(yb + (size_t)v * FTOT + f0 + cb);
            dst[0] = make_uint4(tmp[0],  tmp[1],  tmp[2],  tmp[3]);
            dst[1] = make_uint4(tmp[4],  tmp[5],  tmp[6],  tmp[7]);
            dst[2] = make_uint4(tmp[8],  tmp[9],  tmp[10], tmp[11]);
            dst[3] = make_uint4(tmp[12], tmp[13], tmp[14], tmp[15]);
        }
    }
}

// ---------- Phase 2: CSR gather -> out (each element written exactly once) ----------
__global__ __launch_bounds__(256)
void gather_out(const unsigned short* __restrict__ y, const int* __restrict__ offs,
                const int* __restrict__ bbase, const int* __restrict__ counts,
                const int* __restrict__ csr, float* __restrict__ out, int b_base)
{
    __shared__ float lt[64 * 130];
    const int t = threadIdx.x, lane = t & 63, wvv = t >> 6;
    const int n0 = blockIdx.x * 64;
    const int bl = blockIdx.y;
    const unsigned short* yb = y + (size_t)bl * VLOW * FTOT;

    for (int nl = 0; nl < 16; ++nl) {
        int nloc = wvv * 16 + nl;
        int n = n0 + nloc;
        float a0 = 0.0f, a1 = 0.0f;
        if (n < NUP) {
            int st  = offs[n] + bbase[n >> 10];
            int cnt = counts[n];
            for (int e = 0; e < cnt; ++e) {
                int i = csr[st + e];
                int v = i / 7, k = i - v * 7;
                unsigned int u = *(const unsigned int*)(yb + (size_t)v * FTOT + k * COUT + lane * 2);
                a0 += bflo(u);
                a1 += bfhi(u);
            }
            float inv = cnt ? 1.0f / (float)cnt : 0.0f;
            a0 *= inv; a1 *= inv;
        }
        lt[nloc * 130 + lane * 2]     = a0;
        lt[nloc * 130 + lane * 2 + 1] = a1;
    }
    __syncthreads();

    float* ob = out + (size_t)(b_base + bl) * COUT * NUP;
    int nl2 = t & 63, n = n0 + nl2;
    if (n < NUP) {
#pragma unroll
        for (int rr = 0; rr < 32; ++rr) {
            int c = rr * 4 + (t >> 6);
            ob[(size_t)c * NUP + n] = lt[nl2 * 130 + c];
        }
    }
}

// ---------- launch ----------

extern "C" void kernel_launch(void* const* d_in, const int* in_sizes, int n_in,
                              void* d_out, int out_size, void* d_ws, size_t ws_size,
                              hipStream_t stream) {
    const float* x     = (const float*)d_in[0];
    const float* w     = (const float*)d_in[1];
    const float* bias  = (const float*)d_in[2];
    const int*   neigh = (const int*)d_in[3];
    float* out = (float*)d_out;

    char* p = (char*)d_ws;
    const size_t a_nup = ((size_t)NUP * 4 + 255) & ~(size_t)255;   // 164096
    int* counts = (int*)p;           p += a_nup;
    int* cursor = (int*)p;           p += a_nup;                   // contiguous with counts
    int* offs   = (int*)p;           p += a_nup;
    int* bsum   = (int*)p;           p += 256;
    int* bbase  = (int*)p;           p += 256;
    int* csr    = (int*)p;           p += ((size_t)VK * 4 + 255) & ~(size_t)255;
    unsigned short* wT = (unsigned short*)p;  p += ((size_t)FTOT * 256 * 2 + 255) & ~(size_t)255;

    size_t meta    = (size_t)(p - (char*)d_ws);
    size_t xT_per  = (size_t)VPAD * 256 * 2;      // 5.31 MB
    size_t y_per   = (size_t)VLOW * FTOT * 2;     // 18.35 MB
    int G = 4;
    while (G > 1 && meta + (size_t)G * (xT_per + y_per) > ws_size) G >>= 1;

    unsigned short* xT = (unsigned short*)p;
    unsigned short* y  = (unsigned short*)(p + (size_t)G * xT_per);

    hipMemsetAsync(counts, 0, a_nup * 2, stream);                  // counts + cursor

    count_kernel<<<(VK + 255) / 256, 256, 0, stream>>>(neigh, counts);
    scan_local<<<NBLK, 1024, 0, stream>>>(counts, offs, bsum);
    scan_sums<<<1, 64, 0, stream>>>(bsum, bbase);
    fill_csr<<<(VK + 255) / 256, 256, 0, stream>>>(neigh, offs, bbase, cursor, csr);
    transpose256<<<dim3(FTOT / 64, 4, 1), 256, 0, stream>>>(w, wT, FTOT, FTOT, FTOT);

    for (int bg = 0; bg < B_; bg += G) {
        transpose256<<<dim3(VPAD / 64, 4, G), 256, 0, stream>>>(
            x + (size_t)bg * CIN * VLOW, xT, VLOW, VLOW, VPAD);
        gemm_y<<<dim3(81, KTAP, G), 256, 0, stream>>>(xT, wT, bias, y);
        gather_out<<<dim3(641, G), 256, 0, stream>>>(y, offs, bbase, counts, csr, out, bg);
    }
}

// Round 4
// 881.211 us; speedup vs baseline: 1.2137x; 1.1481x over previous
//
#include <hip/hip_runtime.h>
#include <stdint.h>

#define B_    16
#define CIN   256
#define COUT  128
#define VLOW  10242
#define NUP   40962
#define KTAP  7
#define FTOT  (KTAP * COUT)   // 896
#define VK    (VLOW * KTAP)   // 71694
#define NBLK  41              // ceil(NUP/1024) scan blocks
#define VPAD  10368           // 81*128, padded v rows for xT
#define CSR_CAP 512           // per-64-vertex-block CSR segment capacity (avg ~112)

typedef __attribute__((ext_vector_type(4))) float  floatx4;
typedef __attribute__((ext_vector_type(8))) short  bf16x8;

typedef __attribute__((address_space(3))) unsigned char       lds_u8;
typedef const __attribute__((address_space(1))) unsigned char gbl_u8;

__device__ __forceinline__ void gl_lds16(const unsigned short* g, unsigned short* l) {
    // 64 lanes x 16 B -> LDS[base + lane*16]; global src is per-lane
    __builtin_amdgcn_global_load_lds((gbl_u8*)g, (lds_u8*)l, 16, 0, 0);
}

__device__ __forceinline__ unsigned short f2bf(float f) {
    union { float f; unsigned int u; } x; x.f = f;
    unsigned int r = x.u + 0x7FFFu + ((x.u >> 16) & 1u);  // RNE
    return (unsigned short)(r >> 16);
}
__device__ __forceinline__ float bflo(unsigned int u) {
    union { unsigned int u; float f; } x; x.u = u << 16; return x.f;
}
__device__ __forceinline__ float bfhi(unsigned int u) {
    union { unsigned int u; float f; } x; x.u = u & 0xFFFF0000u; return x.f;
}

// ---------- CSR construction ----------

__global__ void count_kernel(const int* __restrict__ neigh, int* __restrict__ counts) {
    int i = blockIdx.x * blockDim.x + threadIdx.x;
    if (i < VK) atomicAdd(&counts[neigh[i]], 1);
}

__global__ __launch_bounds__(1024)
void scan_local(const int* __restrict__ counts, int* __restrict__ offs, int* __restrict__ bsum) {
    __shared__ int s[1024];
    const int t = threadIdx.x;
    const int idx = blockIdx.x * 1024 + t;
    int v = (idx < NUP) ? counts[idx] : 0;
    s[t] = v;
    __syncthreads();
    int acc = v;
    for (int off = 1; off < 1024; off <<= 1) {
        int add = (t >= off) ? s[t - off] : 0;
        __syncthreads();
        acc += add;
        s[t] = acc;
        __syncthreads();
    }
    if (idx < NUP) offs[idx] = acc - v;
    if (t == 1023) bsum[blockIdx.x] = acc;
}

__global__ void scan_sums(const int* __restrict__ bsum, int* __restrict__ bbase) {
    __shared__ int s[64];
    int t = threadIdx.x;
    s[t] = (t < NBLK) ? bsum[t] : 0;
    __syncthreads();
    if (t == 0) {
        int r = 0;
        for (int j = 0; j < NBLK; ++j) { bbase[j] = r; r += s[j]; }
    }
}

__global__ void fill_csr(const int* __restrict__ neigh, const int* __restrict__ offs,
                         const int* __restrict__ bbase, int* __restrict__ cursor,
                         int* __restrict__ csr) {
    int i = blockIdx.x * blockDim.x + threadIdx.x;
    if (i < VK) {
        int n = neigh[i];
        int p = atomicAdd(&cursor[n], 1);
        csr[offs[n] + bbase[n >> 10] + p] = i;
    }
}

__global__ void make_pos(const int* __restrict__ offs, const int* __restrict__ bbase,
                         int* __restrict__ pos) {
    int i = blockIdx.x * blockDim.x + threadIdx.x;
    if (i <= NUP) pos[i] = (i < NUP) ? (offs[i] + bbase[i >> 10]) : VK;
}

// ---------- fp32 [256][C] -> bf16 [CPAD][256] transpose+convert ----------
__global__ __launch_bounds__(256)
void transpose256(const float* __restrict__ src, unsigned short* __restrict__ dst,
                  int C, int CLIM, int CPAD)
{
    __shared__ unsigned short lt[64][72];
    const int t  = threadIdx.x;
    const int v0 = blockIdx.x * 64;
    const int c0 = blockIdx.y * 64;
    const int z  = blockIdx.z;
    const float* s = src + (size_t)z * 256 * C;
    unsigned short* d = dst + (size_t)z * CPAD * 256;

#pragma unroll
    for (int p = 0; p < 16; ++p) {
        int cr = c0 + p * 4 + (t >> 6);
        int v  = v0 + (t & 63);
        float val = (v < CLIM) ? s[(size_t)cr * C + v] : 0.0f;
        lt[t & 63][p * 4 + (t >> 6)] = f2bf(val);
    }
    __syncthreads();
    // 256 threads x 16 B = 2048 shorts/iter; 64x64 tile = 4096 shorts -> 2 iters
#pragma unroll
    for (int p = 0; p < 2; ++p) {
        int vl = p * 32 + (t >> 3);
        int v  = v0 + vl;
        if (v < CPAD) {
            uint4 val = *(const uint4*)&lt[vl][(t & 7) * 8];
            *(uint4*)&d[(size_t)v * 256 + c0 + (t & 7) * 8] = val;
        }
    }
}

// ---------- Phase 1: GEMM -> y (bf16), 2-phase double-buffered staging ----------
// Block: 256 threads (4 waves). Tile: 128 v x 128 f (f-tile == one tap k).
// LDS: 2 x { A [128][32], B [128][32] } = 32 KB; pool reused for epilogue transpose.
__global__ __launch_bounds__(256)
void gemm_y(const unsigned short* __restrict__ xT,  // [G][VPAD][256] bf16
            const unsigned short* __restrict__ wT,  // [896][256] bf16
            const float* __restrict__ bias,         // [FTOT]
            unsigned short* __restrict__ y)         // [G][VLOW][FTOT] bf16
{
    __shared__ unsigned short smem[16384];
    unsigned short* A0 = smem;            // [128][32]
    unsigned short* B0 = smem + 4096;
    unsigned short* A1 = smem + 8192;
    unsigned short* B1 = smem + 12288;

    const int t    = threadIdx.x;
    const int vt   = blockIdx.x;       // 0..80
    const int ktap = blockIdx.y;       // 0..6
    const int bl   = blockIdx.z;       // batch
    const int v0   = vt * 128;
    const int f0   = ktap * 128;

    const int lane = t & 63;
    const int wid  = t >> 6;
    const int wv   = wid & 1;
    const int wf   = wid >> 1;
    const int mrow = lane & 15;
    const int quad = lane >> 4;
    const int kb   = quad * 8;

    floatx4 acc[4][4];
#pragma unroll
    for (int i = 0; i < 4; i++)
#pragma unroll
        for (int j = 0; j < 4; j++) acc[i][j] = (floatx4)0.0f;

    // staging: wave w stages A rows [32w, 32w+32) and same B rows.
    // one instr covers 16 rows: lane l -> row l>>2, 16B chunk l&3 (row = 64 B)
    const int srow = (lane >> 2);
    const int scol = (lane & 3) << 3;   // bf16 elems
    const unsigned short* gA0 = xT + (((size_t)bl * VPAD + v0 + wid * 32 + srow) << 8) + scol;
    const unsigned short* gA1 = gA0 + (16 << 8);
    const unsigned short* gB0 = wT + (((size_t)f0 + wid * 32 + srow) << 8) + scol;
    const unsigned short* gB1 = gB0 + (16 << 8);
    const int woff = wid * 1024;   // wave's LDS write base (shorts)

#define STAGE(AB, BB, KC) do {                        \
        gl_lds16(gA0 + (KC), (AB) + woff);            \
        gl_lds16(gA1 + (KC), (AB) + woff + 512);      \
        gl_lds16(gB0 + (KC), (BB) + woff);            \
        gl_lds16(gB1 + (KC), (BB) + woff + 512);      \
    } while (0)

#define COMPUTE(AB, BB) do {                                                        \
        bf16x8 fa[4], fb[4];                                                        \
        _Pragma("unroll")                                                           \
        for (int i = 0; i < 4; i++)                                                 \
            fa[i] = *(const bf16x8*)&(AB)[(wv * 64 + i * 16 + mrow) * 32 + kb];     \
        _Pragma("unroll")                                                           \
        for (int j = 0; j < 4; j++)                                                 \
            fb[j] = *(const bf16x8*)&(BB)[(wf * 64 + j * 16 + mrow) * 32 + kb];     \
        _Pragma("unroll")                                                           \
        for (int i = 0; i < 4; i++)                                                 \
            _Pragma("unroll")                                                       \
            for (int j = 0; j < 4; j++)                                             \
                acc[i][j] = __builtin_amdgcn_mfma_f32_16x16x32_bf16(fa[i], fb[j],   \
                                                                    acc[i][j], 0, 0, 0); \
    } while (0)

    STAGE(A0, B0, 0);
    __syncthreads();                       // barrier auto-drains vmcnt
#pragma unroll
    for (int tt = 0; tt < 4; ++tt) {
        const int kc = tt * 64;
        if (kc + 32 < CIN) STAGE(A1, B1, kc + 32);   // prefetch overlaps compute
        COMPUTE(A0, B0);
        __syncthreads();
        if (kc + 64 < CIN) STAGE(A0, B0, kc + 64);
        COMPUTE(A1, B1);
        __syncthreads();
    }
#undef STAGE
#undef COMPUTE

    // epilogue: +bias, bf16, LDS transpose, coalesced 16B stores
    float bvv[4];
#pragma unroll
    for (int j = 0; j < 4; j++) bvv[j] = bias[f0 + wf * 64 + j * 16 + mrow];

    unsigned short* yb = y + (size_t)bl * VLOW * FTOT;
#pragma unroll
    for (int half = 0; half < 2; ++half) {
        __syncthreads();
        if (wv == half) {
#pragma unroll
            for (int i = 0; i < 4; i++)
#pragma unroll
                for (int j = 0; j < 4; j++)
#pragma unroll
                    for (int r = 0; r < 4; r++) {
                        int vl = i * 16 + quad * 4 + r;            // 0..63
                        int c  = wf * 64 + j * 16 + mrow;          // 0..127
                        smem[vl * 130 + c] = f2bf(acc[i][j][r] + bvv[j]);
                    }
        }
        __syncthreads();
        int row = t >> 2, cb = (t & 3) * 32;
        int v = v0 + half * 64 + row;
        if (v < VLOW) {
            unsigned int tmp[16];
#pragma unroll
            for (int q = 0; q < 16; q++)
                tmp[q] = *(const unsigned int*)&smem[row * 130 + cb + q * 2];
            uint4* dst = (uint4*)(yb + (size_t)v * FTOT + f0 + cb);
            dst[0] = make_uint4(tmp[0],  tmp[1],  tmp[2],  tmp[3]);
            dst[1] = make_uint4(tmp[4],  tmp[5],  tmp[6],  tmp[7]);
            dst[2] = make_uint4(tmp[8],  tmp[9],  tmp[10], tmp[11]);
            dst[3] = make_uint4(tmp[12], tmp[13], tmp[14], tmp[15]);
        }
    }
}

// ---------- Phase 2: CSR gather -> out ----------
// Block: 256 threads, 64 up-vertices x one batch. LDS-resident pos/csr segment
// (CSR is n-sorted => block's entries contiguous). y offset of entry i = i*128 shorts.
__global__ __launch_bounds__(256)
void gather_out(const unsigned short* __restrict__ y, const int* __restrict__ pos,
                const int* __restrict__ csr, float* __restrict__ out)
{
    __shared__ int   s_pos[65];
    __shared__ int   s_csr[CSR_CAP];
    __shared__ float lt[64 * 130];
    const int t = threadIdx.x, lane = t & 63, wvv = t >> 6;
    const int n0 = blockIdx.x * 64;
    const int bl = blockIdx.y;
    const unsigned short* yb = y + (size_t)bl * VLOW * FTOT;

    if (t < 65) {
        int idx = n0 + t; if (idx > NUP) idx = NUP;
        s_pos[t] = pos[idx];
    }
    __syncthreads();
    const int S = s_pos[0];
    const int num = s_pos[64] - S;
    const bool fits = (num <= CSR_CAP);
    if (fits) for (int i = t; i < num; i += 256) s_csr[i] = csr[S + i];
    __syncthreads();

#pragma unroll
    for (int nl = 0; nl < 16; ++nl) {
        const int nloc = wvv * 16 + nl;
        const int st  = s_pos[nloc] - S;
        const int cnt = s_pos[nloc + 1] - s_pos[nloc];
        float a0 = 0.0f, a1 = 0.0f;
        int e = 0;
        for (; e + 2 <= cnt; e += 2) {            // paired independent loads
            int i0 = fits ? s_csr[st + e]     : csr[S + st + e];
            int i1 = fits ? s_csr[st + e + 1] : csr[S + st + e + 1];
            unsigned u0 = *(const unsigned int*)(yb + (((size_t)i0) << 7) + lane * 2);
            unsigned u1 = *(const unsigned int*)(yb + (((size_t)i1) << 7) + lane * 2);
            a0 += bflo(u0) + bflo(u1);
            a1 += bfhi(u0) + bfhi(u1);
        }
        if (e < cnt) {
            int i0 = fits ? s_csr[st + e] : csr[S + st + e];
            unsigned u0 = *(const unsigned int*)(yb + (((size_t)i0) << 7) + lane * 2);
            a0 += bflo(u0);
            a1 += bfhi(u0);
        }
        float inv = cnt ? 1.0f / (float)cnt : 0.0f;
        lt[nloc * 130 + lane * 2]     = a0 * inv;
        lt[nloc * 130 + lane * 2 + 1] = a1 * inv;
    }
    __syncthreads();

    float* ob = out + (size_t)bl * COUT * NUP;
    int nl2 = t & 63, n = n0 + nl2;
    if (n < NUP) {
#pragma unroll
        for (int rr = 0; rr < 32; ++rr) {
            int c = rr * 4 + (t >> 6);
            ob[(size_t)c * NUP + n] = lt[nl2 * 130 + c];
        }
    }
}

// ---------- launch ----------

extern "C" void kernel_launch(void* const* d_in, const int* in_sizes, int n_in,
                              void* d_out, int out_size, void* d_ws, size_t ws_size,
                              hipStream_t stream) {
    const float* x     = (const float*)d_in[0];
    const float* w     = (const float*)d_in[1];
    const float* bias  = (const float*)d_in[2];
    const int*   neigh = (const int*)d_in[3];
    float* out = (float*)d_out;

    char* p = (char*)d_ws;
    const size_t a_nup = ((size_t)NUP * 4 + 255) & ~(size_t)255;   // 164096
    int* counts = (int*)p;           p += a_nup;
    int* cursor = (int*)p;           p += a_nup;                   // contiguous with counts
    int* offs   = (int*)p;           p += a_nup;
    int* pos    = (int*)p;           p += a_nup + 256;             // NUP+1 ints
    int* bsum   = (int*)p;           p += 256;
    int* bbase  = (int*)p;           p += 256;
    int* csr    = (int*)p;           p += ((size_t)VK * 4 + 255) & ~(size_t)255;
    unsigned short* wT = (unsigned short*)p;  p += ((size_t)FTOT * 256 * 2 + 255) & ~(size_t)255;

    size_t meta    = (size_t)(p - (char*)d_ws);
    size_t xT_per  = (size_t)VPAD * 256 * 2;      // 5.31 MB
    size_t y_per   = (size_t)VLOW * FTOT * 2;     // 18.35 MB
    int G = 16;
    while (G > 1 && meta + (size_t)G * (xT_per + y_per) > ws_size) G >>= 1;

    unsigned short* xT = (unsigned short*)p;
    unsigned short* y  = (unsigned short*)(p + (size_t)G * xT_per);

    hipMemsetAsync(counts, 0, a_nup * 2, stream);                  // counts + cursor

    count_kernel<<<(VK + 255) / 256, 256, 0, stream>>>(neigh, counts);
    scan_local<<<NBLK, 1024, 0, stream>>>(counts, offs, bsum);
    scan_sums<<<1, 64, 0, stream>>>(bsum, bbase);
    fill_csr<<<(VK + 255) / 256, 256, 0, stream>>>(neigh, offs, bbase, cursor, csr);
    make_pos<<<(NUP + 256) / 256, 256, 0, stream>>>(offs, bbase, pos);
    transpose256<<<dim3(FTOT / 64, 4, 1), 256, 0, stream>>>(w, wT, FTOT, FTOT, FTOT);

    for (int bg = 0; bg < B_; bg += G) {
        transpose256<<<dim3(VPAD / 64, 4, G), 256, 0, stream>>>(
            x + (size_t)bg * CIN * VLOW, xT, VLOW, VLOW, VPAD);
        gemm_y<<<dim3(81, KTAP, G), 256, 0, stream>>>(xT, wT, bias, y);
        gather_out<<<dim3(641, G), 256, 0, stream>>>(
            y, pos, csr, out + (size_t)bg * COUT * NUP);
    }
}

// Round 5
// 850.722 us; speedup vs baseline: 1.2571x; 1.0358x over previous
//
#include <hip/hip_runtime.h>
#include <stdint.h>

#define B_    16
#define CIN   256
#define COUT  128
#define VLOW  10242
#define NUP   40962
#define KTAP  7
#define FTOT  (KTAP * COUT)   // 896
#define VK    (VLOW * KTAP)   // 71694
#define NBLK  41              // ceil(NUP/1024) scan blocks
#define VPAD  10368           // 81*128, padded v rows for xT
#define CSR_CAP 512           // per-64-vertex-block CSR capacity (mean 112)
#define GCAP  112             // staged y-rows per 32-n half (mean 56, P(>112)~1e-18)

typedef __attribute__((ext_vector_type(4))) float  floatx4;
typedef __attribute__((ext_vector_type(8))) short  bf16x8;

typedef __attribute__((address_space(3))) unsigned char       lds_u8;
typedef const __attribute__((address_space(1))) unsigned char gbl_u8;

__device__ __forceinline__ void gl_lds16(const unsigned short* g, unsigned short* l) {
    // 64 lanes x 16 B -> LDS[base + lane*16]; global src is per-lane
    __builtin_amdgcn_global_load_lds((gbl_u8*)g, (lds_u8*)l, 16, 0, 0);
}

__device__ __forceinline__ unsigned short f2bf(float f) {
    union { float f; unsigned int u; } x; x.f = f;
    unsigned int r = x.u + 0x7FFFu + ((x.u >> 16) & 1u);  // RNE
    return (unsigned short)(r >> 16);
}
__device__ __forceinline__ float bflo(unsigned int u) {
    union { unsigned int u; float f; } x; x.u = u << 16; return x.f;
}
__device__ __forceinline__ float bfhi(unsigned int u) {
    union { unsigned int u; float f; } x; x.u = u & 0xFFFF0000u; return x.f;
}

// ---------- CSR construction ----------

__global__ void count_kernel(const int* __restrict__ neigh, int* __restrict__ counts) {
    int i = blockIdx.x * blockDim.x + threadIdx.x;
    if (i < VK) atomicAdd(&counts[neigh[i]], 1);
}

__global__ __launch_bounds__(1024)
void scan_local(const int* __restrict__ counts, int* __restrict__ offs, int* __restrict__ bsum) {
    __shared__ int s[1024];
    const int t = threadIdx.x;
    const int idx = blockIdx.x * 1024 + t;
    int v = (idx < NUP) ? counts[idx] : 0;
    s[t] = v;
    __syncthreads();
    int acc = v;
    for (int off = 1; off < 1024; off <<= 1) {
        int add = (t >= off) ? s[t - off] : 0;
        __syncthreads();
        acc += add;
        s[t] = acc;
        __syncthreads();
    }
    if (idx < NUP) offs[idx] = acc - v;
    if (t == 1023) bsum[blockIdx.x] = acc;
}

__global__ void scan_sums(const int* __restrict__ bsum, int* __restrict__ bbase) {
    __shared__ int s[64];
    int t = threadIdx.x;
    s[t] = (t < NBLK) ? bsum[t] : 0;
    __syncthreads();
    if (t == 0) {
        int r = 0;
        for (int j = 0; j < NBLK; ++j) { bbase[j] = r; r += s[j]; }
    }
}

__global__ void fill_csr(const int* __restrict__ neigh, const int* __restrict__ offs,
                         const int* __restrict__ bbase, int* __restrict__ cursor,
                         int* __restrict__ csr) {
    int i = blockIdx.x * blockDim.x + threadIdx.x;
    if (i < VK) {
        int n = neigh[i];
        int p = atomicAdd(&cursor[n], 1);
        csr[offs[n] + bbase[n >> 10] + p] = i;
    }
}

__global__ void make_pos(const int* __restrict__ offs, const int* __restrict__ bbase,
                         int* __restrict__ pos) {
    int i = blockIdx.x * blockDim.x + threadIdx.x;
    if (i <= NUP) pos[i] = (i < NUP) ? (offs[i] + bbase[i >> 10]) : VK;
}

// ---------- fp32 [256][C] -> bf16 [CPAD][256] transpose+convert ----------
__global__ __launch_bounds__(256)
void transpose256(const float* __restrict__ src, unsigned short* __restrict__ dst,
                  int C, int CLIM, int CPAD)
{
    __shared__ unsigned short lt[64][72];
    const int t  = threadIdx.x;
    const int v0 = blockIdx.x * 64;
    const int c0 = blockIdx.y * 64;
    const int z  = blockIdx.z;
    const float* s = src + (size_t)z * 256 * C;
    unsigned short* d = dst + (size_t)z * CPAD * 256;

#pragma unroll
    for (int p = 0; p < 16; ++p) {
        int cr = c0 + p * 4 + (t >> 6);
        int v  = v0 + (t & 63);
        float val = (v < CLIM) ? s[(size_t)cr * C + v] : 0.0f;
        lt[t & 63][p * 4 + (t >> 6)] = f2bf(val);
    }
    __syncthreads();
    // 256 threads x 16 B = 2048 shorts/iter; 64x64 tile = 4096 shorts -> 2 iters
#pragma unroll
    for (int p = 0; p < 2; ++p) {
        int vl = p * 32 + (t >> 3);
        int v  = v0 + vl;
        if (v < CPAD) {
            uint4 val = *(const uint4*)&lt[vl][(t & 7) * 8];
            *(uint4*)&d[(size_t)v * 256 + c0 + (t & 7) * 8] = val;
        }
    }
}

// ---------- Phase 1: GEMM -> y (bf16), 2-phase double-buffered staging ----------
__global__ __launch_bounds__(256)
void gemm_y(const unsigned short* __restrict__ xT,  // [G][VPAD][256] bf16
            const unsigned short* __restrict__ wT,  // [896][256] bf16
            const float* __restrict__ bias,         // [FTOT]
            unsigned short* __restrict__ y)         // [G][VLOW][FTOT] bf16
{
    __shared__ unsigned short smem[16384];
    unsigned short* A0 = smem;            // [128][32]
    unsigned short* B0 = smem + 4096;
    unsigned short* A1 = smem + 8192;
    unsigned short* B1 = smem + 12288;

    const int t    = threadIdx.x;
    const int vt   = blockIdx.x;       // 0..80
    const int ktap = blockIdx.y;       // 0..6
    const int bl   = blockIdx.z;       // batch
    const int v0   = vt * 128;
    const int f0   = ktap * 128;

    const int lane = t & 63;
    const int wid  = t >> 6;
    const int wv   = wid & 1;
    const int wf   = wid >> 1;
    const int mrow = lane & 15;
    const int quad = lane >> 4;
    const int kb   = quad * 8;

    floatx4 acc[4][4];
#pragma unroll
    for (int i = 0; i < 4; i++)
#pragma unroll
        for (int j = 0; j < 4; j++) acc[i][j] = (floatx4)0.0f;

    const int srow = (lane >> 2);
    const int scol = (lane & 3) << 3;   // bf16 elems
    const unsigned short* gA0 = xT + (((size_t)bl * VPAD + v0 + wid * 32 + srow) << 8) + scol;
    const unsigned short* gA1 = gA0 + (16 << 8);
    const unsigned short* gB0 = wT + (((size_t)f0 + wid * 32 + srow) << 8) + scol;
    const unsigned short* gB1 = gB0 + (16 << 8);
    const int woff = wid * 1024;   // wave's LDS write base (shorts)

#define STAGE(AB, BB, KC) do {                        \
        gl_lds16(gA0 + (KC), (AB) + woff);            \
        gl_lds16(gA1 + (KC), (AB) + woff + 512);      \
        gl_lds16(gB0 + (KC), (BB) + woff);            \
        gl_lds16(gB1 + (KC), (BB) + woff + 512);      \
    } while (0)

#define COMPUTE(AB, BB) do {                                                        \
        bf16x8 fa[4], fb[4];                                                        \
        _Pragma("unroll")                                                           \
        for (int i = 0; i < 4; i++)                                                 \
            fa[i] = *(const bf16x8*)&(AB)[(wv * 64 + i * 16 + mrow) * 32 + kb];     \
        _Pragma("unroll")                                                           \
        for (int j = 0; j < 4; j++)                                                 \
            fb[j] = *(const bf16x8*)&(BB)[(wf * 64 + j * 16 + mrow) * 32 + kb];     \
        _Pragma("unroll")                                                           \
        for (int i = 0; i < 4; i++)                                                 \
            _Pragma("unroll")                                                       \
            for (int j = 0; j < 4; j++)                                             \
                acc[i][j] = __builtin_amdgcn_mfma_f32_16x16x32_bf16(fa[i], fb[j],   \
                                                                    acc[i][j], 0, 0, 0); \
    } while (0)

    STAGE(A0, B0, 0);
    __syncthreads();
#pragma unroll
    for (int tt = 0; tt < 4; ++tt) {
        const int kc = tt * 64;
        if (kc + 32 < CIN) STAGE(A1, B1, kc + 32);
        COMPUTE(A0, B0);
        __syncthreads();
        if (kc + 64 < CIN) STAGE(A0, B0, kc + 64);
        COMPUTE(A1, B1);
        __syncthreads();
    }
#undef STAGE
#undef COMPUTE

    float bvv[4];
#pragma unroll
    for (int j = 0; j < 4; j++) bvv[j] = bias[f0 + wf * 64 + j * 16 + mrow];

    unsigned short* yb = y + (size_t)bl * VLOW * FTOT;
#pragma unroll
    for (int half = 0; half < 2; ++half) {
        __syncthreads();
        if (wv == half) {
#pragma unroll
            for (int i = 0; i < 4; i++)
#pragma unroll
                for (int j = 0; j < 4; j++)
#pragma unroll
                    for (int r = 0; r < 4; r++) {
                        int vl = i * 16 + quad * 4 + r;            // 0..63
                        int c  = wf * 64 + j * 16 + mrow;          // 0..127
                        smem[vl * 130 + c] = f2bf(acc[i][j][r] + bvv[j]);
                    }
        }
        __syncthreads();
        int row = t >> 2, cb = (t & 3) * 32;
        int v = v0 + half * 64 + row;
        if (v < VLOW) {
            unsigned int tmp[16];
#pragma unroll
            for (int q = 0; q < 16; q++)
                tmp[q] = *(const unsigned int*)&smem[row * 130 + cb + q * 2];
            uint4* dst = (uint4*)(yb + (size_t)v * FTOT + f0 + cb);
            dst[0] = make_uint4(tmp[0],  tmp[1],  tmp[2],  tmp[3]);
            dst[1] = make_uint4(tmp[4],  tmp[5],  tmp[6],  tmp[7]);
            dst[2] = make_uint4(tmp[8],  tmp[9],  tmp[10], tmp[11]);
            dst[3] = make_uint4(tmp[12], tmp[13], tmp[14], tmp[15]);
        }
    }
}

// ---------- Phase 2: CSR gather -> out, decoupled load/reduce ----------
// Block: 256 threads, 64 n x one batch, processed as 2 halves of 32 n.
// Phase A: bulk-stage the half's y-rows into LDS (independent uint4 loads,
// col-XOR swizzle). Phase B: thread = (n, 16-c slice); LDS reads + direct
// coalesced stores (no transpose buffer).
__global__ __launch_bounds__(256)
void gather_out(const unsigned short* __restrict__ y, const int* __restrict__ pos,
                const int* __restrict__ csr, float* __restrict__ out)
{
    __shared__ int   s_pos[65];
    __shared__ int   s_csr[CSR_CAP];
    __shared__ unsigned short s_rows[GCAP * 128];   // staged y-rows, swizzled
    const int t  = threadIdx.x;
    const int n0 = blockIdx.x * 64;
    const int bl = blockIdx.y;
    const unsigned short* yb = y + (size_t)bl * VLOW * FTOT;
    float* ob = out + (size_t)bl * COUT * NUP;

    if (t < 65) {
        int idx = n0 + t; if (idx > NUP) idx = NUP;
        s_pos[t] = pos[idx];
    }
    __syncthreads();
    const int S   = s_pos[0];
    const int num = s_pos[64] - S;
    const bool csr_fits = (num <= CSR_CAP);
    if (csr_fits) for (int i = t; i < num; i += 256) s_csr[i] = csr[S + i];
    __syncthreads();

    const int nl = t & 31;          // n within half
    const int cg = t >> 5;          // c-group 0..7 (16 channels each)

#pragma unroll
    for (int h = 0; h < 2; ++h) {
        const int stH  = s_pos[h * 32] - S;
        const int numH = s_pos[h * 32 + 32] - S - stH;
        const bool staged = csr_fits && (numH <= GCAP);

        if (staged) {
            // 16 rows per iteration: 16 lanes x 16B per row, loads independent
            for (int e0 = 0; e0 < numH; e0 += 16) {
                int e = e0 + (t >> 4);
                if (e < numH) {
                    int i = s_csr[stH + e];
                    uint4 d = *(const uint4*)(yb + (((size_t)i) << 7) + (t & 15) * 8);
                    int cq = ((t & 15) * 4) ^ ((e & 15) << 2);   // dword-col swizzle
                    *(uint4*)((char*)s_rows + e * 256 + cq * 4) = d;
                }
            }
        }
        __syncthreads();

        const int nloc = h * 32 + nl;
        const int stN  = s_pos[nloc] - S;
        const int cnt  = s_pos[nloc + 1] - s_pos[nloc];
        float acc[16];
#pragma unroll
        for (int k = 0; k < 16; ++k) acc[k] = 0.0f;

        for (int e = 0; e < cnt; ++e) {
            uint4 d0, d1;
            if (staged) {
                int r   = stN - stH + e;
                int cq0 = (cg * 8)     ^ ((r & 15) << 2);
                int cq1 = (cg * 8 + 4) ^ ((r & 15) << 2);
                d0 = *(const uint4*)((const char*)s_rows + r * 256 + cq0 * 4);
                d1 = *(const uint4*)((const char*)s_rows + r * 256 + cq1 * 4);
            } else {
                int i = csr_fits ? s_csr[stN + e] : csr[S + stN + e];
                const unsigned short* row = yb + (((size_t)i) << 7);
                d0 = *(const uint4*)(row + cg * 16);
                d1 = *(const uint4*)(row + cg * 16 + 8);
            }
            acc[0]  += bflo(d0.x); acc[1]  += bfhi(d0.x);
            acc[2]  += bflo(d0.y); acc[3]  += bfhi(d0.y);
            acc[4]  += bflo(d0.z); acc[5]  += bfhi(d0.z);
            acc[6]  += bflo(d0.w); acc[7]  += bfhi(d0.w);
            acc[8]  += bflo(d1.x); acc[9]  += bfhi(d1.x);
            acc[10] += bflo(d1.y); acc[11] += bfhi(d1.y);
            acc[12] += bflo(d1.z); acc[13] += bfhi(d1.z);
        // d1.w
            acc[14] += bflo(d1.w); acc[15] += bfhi(d1.w);
        }

        int n = n0 + nloc;
        if (n < NUP) {
            float inv = cnt ? 1.0f / (float)cnt : 0.0f;
#pragma unroll
            for (int k = 0; k < 16; ++k)
                ob[(size_t)(cg * 16 + k) * NUP + n] = acc[k] * inv;
        }
        __syncthreads();   // s_rows safe to overwrite next half
    }
}

// ---------- launch ----------

extern "C" void kernel_launch(void* const* d_in, const int* in_sizes, int n_in,
                              void* d_out, int out_size, void* d_ws, size_t ws_size,
                              hipStream_t stream) {
    const float* x     = (const float*)d_in[0];
    const float* w     = (const float*)d_in[1];
    const float* bias  = (const float*)d_in[2];
    const int*   neigh = (const int*)d_in[3];
    float* out = (float*)d_out;

    char* p = (char*)d_ws;
    const size_t a_nup = ((size_t)NUP * 4 + 255) & ~(size_t)255;   // 164096
    int* counts = (int*)p;           p += a_nup;
    int* cursor = (int*)p;           p += a_nup;                   // contiguous with counts
    int* offs   = (int*)p;           p += a_nup;
    int* pos    = (int*)p;           p += a_nup + 256;             // NUP+1 ints
    int* bsum   = (int*)p;           p += 256;
    int* bbase  = (int*)p;           p += 256;
    int* csr    = (int*)p;           p += ((size_t)VK * 4 + 255) & ~(size_t)255;
    unsigned short* wT = (unsigned short*)p;  p += ((size_t)FTOT * 256 * 2 + 255) & ~(size_t)255;

    size_t meta    = (size_t)(p - (char*)d_ws);
    size_t xT_per  = (size_t)VPAD * 256 * 2;      // 5.31 MB
    size_t y_per   = (size_t)VLOW * FTOT * 2;     // 18.35 MB
    int G = 16;
    while (G > 1 && meta + (size_t)G * (xT_per + y_per) > ws_size) G >>= 1;

    unsigned short* xT = (unsigned short*)p;
    unsigned short* y  = (unsigned short*)(p + (size_t)G * xT_per);

    hipMemsetAsync(counts, 0, a_nup * 2, stream);                  // counts + cursor

    count_kernel<<<(VK + 255) / 256, 256, 0, stream>>>(neigh, counts);
    scan_local<<<NBLK, 1024, 0, stream>>>(counts, offs, bsum);
    scan_sums<<<1, 64, 0, stream>>>(bsum, bbase);
    fill_csr<<<(VK + 255) / 256, 256, 0, stream>>>(neigh, offs, bbase, cursor, csr);
    make_pos<<<(NUP + 256) / 256, 256, 0, stream>>>(offs, bbase, pos);
    transpose256<<<dim3(FTOT / 64, 4, 1), 256, 0, stream>>>(w, wT, FTOT, FTOT, FTOT);

    for (int bg = 0; bg < B_; bg += G) {
        transpose256<<<dim3(VPAD / 64, 4, G), 256, 0, stream>>>(
            x + (size_t)bg * CIN * VLOW, xT, VLOW, VLOW, VPAD);
        gemm_y<<<dim3(81, KTAP, G), 256, 0, stream>>>(xT, wT, bias, y);
        gather_out<<<dim3(641, G), 256, 0, stream>>>(
            y, pos, csr, out + (size_t)bg * COUT * NUP);
    }
}